// Round 6
// baseline (60.533 us; speedup 1.0000x reference)
//
#include <hip/hip_runtime.h>
#include <stdint.h>

// Problem: B=32, P=16, E=50000, H=128
#define E_DIM 50000
#define EP    50048          // E padded to multiple of 64; 46 * 1088 exactly
#define HD    128
#define BD    32
#define PD    16
#define MD    512            // B*P
#define BM    32             // rows per block
#define BK    64             // k per stage
#define KCHUNK 1088          // 17 stages of BK=64
#define NKC   46             // EP / KCHUNK exactly — no short chunk
#define NST   17
#define EPSF  1e-5f

typedef short short8 __attribute__((ext_vector_type(8)));   // 8 bf16 (4 VGPRs)
typedef float f32x4  __attribute__((ext_vector_type(4)));

__device__ __forceinline__ uint16_t f2bf(float f) {
  uint32_t u = __float_as_uint(f);
  u += 0x7FFFu + ((u >> 16) & 1u);           // round-to-nearest-even
  return (uint16_t)(u >> 16);
}

// ---------------------------------------------------------------------------
// Kernel 1: emb [E][H] fp32 -> embF MFMA-fragment-packed bf16.
// Block bid covers e0 = bid*64 (bid = kc*17 + s). Output region per block:
// 16 fragments of 1 KB: [w:4][fr:4][lane:64][8 bf16], where
// fr = kk*2+hfl, h = (2w+hfl)*16 + (lane&15), e = e0 + kk*32 + (lane>>4)*8 + j.
// Row e=0 zeroed (padding_idx), e >= E_DIM zero-padded.
// ---------------------------------------------------------------------------
__global__ __launch_bounds__(256) void k_embF(const float* __restrict__ emb,
                                              uint16_t* __restrict__ embF) {
  __shared__ __align__(16) uint16_t lds[HD * 64];   // [h][e_local], swizzled
  const int t  = threadIdx.x;
  const int e0 = blockIdx.x * 64;

#pragma unroll
  for (int pass = 0; pass < 8; ++pass) {
    const int el = pass * 8 + (t >> 5);       // 0..63
    const int h  = (t & 31) * 4;              // 0..124
    const int eg = e0 + el;
    float4 v = {0.f, 0.f, 0.f, 0.f};
    if (eg < E_DIM && eg != 0)                // padding_idx=0 -> zero row
      v = *(const float4*)(emb + (size_t)eg * HD + h);
    const uint16_t q0 = f2bf(v.x), q1 = f2bf(v.y), q2 = f2bf(v.z), q3 = f2bf(v.w);
    lds[(h + 0) * 64 + (el ^ (((h + 0) & 7) << 3))] = q0;
    lds[(h + 1) * 64 + (el ^ (((h + 1) & 7) << 3))] = q1;
    lds[(h + 2) * 64 + (el ^ (((h + 2) & 7) << 3))] = q2;
    lds[(h + 3) * 64 + (el ^ (((h + 3) & 7) << 3))] = q3;
  }
  __syncthreads();

  const int w    = t >> 6;
  const int lane = t & 63;
  const int r16  = lane & 15;
  const int kgq  = (lane >> 4) * 8;
  uint16_t* outp = embF + (size_t)blockIdx.x * 8192 + (size_t)w * 2048 + lane * 8;
#pragma unroll
  for (int fr = 0; fr < 4; ++fr) {
    const int h  = (2 * w + (fr & 1)) * 16 + r16;
    const int el = (fr >> 1) * 32 + kgq;
    // el % 8 == 0 and the XOR swizzle only touches bits 3..5, so the
    // 8-element (16 B) group stays contiguous after swizzle.
    short8 d = *(const short8*)(lds + h * 64 + (el ^ ((h & 7) << 3)));
    *(short8*)(outp + fr * 512) = d;
  }
}

// ---------------------------------------------------------------------------
// Kernel 2: partial GEMM, deep counted-waitcnt pipeline.
// 17 fully-static phases per block (no runtime guards). A prefetched 4
// phases ahead (4 reg sets), B 2 ahead (3 reg sets), LDS A double-buffered.
// Barriers drain lgkmcnt only — global loads stay in flight across them.
// Grid = 46*16 = 736 blocks = one full generation at 3 blocks/CU.
// ---------------------------------------------------------------------------
__global__ __launch_bounds__(256, 3) void k_gemm(const int* __restrict__ inp,
                                                 const uint16_t* __restrict__ embF,
                                                 float* __restrict__ part,
                                                 float* __restrict__ cntp) {
  __shared__ __align__(16) uint16_t ldsA[2][BM * BK];   // 2 x 4 KB, swizzled

  const int t    = threadIdx.x;
  const int lane = t & 63;
  const int w    = t >> 6;

  // XCD-aware swizzle: 16 blocks sharing a kc land on one XCD (736 = 8*92).
  const int virt = (blockIdx.x & 7) * (NKC * 16 / 8) + (blockIdx.x >> 3);
  const int mb = virt & 15;
  const int kc = virt >> 4;
  const int e0 = kc * KCHUNK;

  // --- A staging map: row sr (0..31), 8 ints at col sc ---
  const int sr = t >> 3;
  const int sc = (t & 7) * 8;
  const int* ap = inp + (size_t)(mb * BM + sr) * E_DIM + e0 + sc;
  const int aw = sr * 128 + (((t & 7) ^ (sr & 7)) << 4);   // swizzled byte off

  // --- B fragment base: per (kc, s, w): 4 x 1 KB contiguous ---
  const uint16_t* bp = embF + ((size_t)kc * NST) * 8192 + (size_t)w * 2048 + lane * 8;

  // --- compute-side LDS read byte offsets (4 constants) ---
  const int r16  = lane & 15;
  const int kg3  = (lane >> 4);               // 0..3 (k-block within step)
  const int swr  = r16 & 7;
  const int aoff = r16 * 128;
  const int o00 = aoff + ((kg3 ^ swr) << 4);          // kk=0, rows 0..15
  const int o01 = o00 + 2048;                         // kk=0, rows 16..31
  const int o10 = aoff + (((4 + kg3) ^ swr) << 4);    // kk=1, rows 0..15
  const int o11 = o10 + 2048;                         // kk=1, rows 16..31

  f32x4 acc00 = {0.f,0.f,0.f,0.f}, acc01 = {0.f,0.f,0.f,0.f};
  f32x4 acc10 = {0.f,0.f,0.f,0.f}, acc11 = {0.f,0.f,0.f,0.f};
  uint32_t cnt = 0;

  // pipeline registers: 4 A sets, 3 B sets (all statically named)
  int4 a0x, a0y, a1x, a1y, a2x, a2y, a3x, a3y;
  short8 t00, t01, t02, t03, t10, t11, t12, t13, t20, t21, t22, t23;

#define LOAD_A(AX, AY, SIG)                                       \
  AX = (int4){0,0,0,0}; AY = (int4){0,0,0,0};                     \
  if (e0 + (SIG) * 64 + sc < E_DIM) {                             \
    AX = *(const int4*)(ap + (SIG) * 64);                         \
    AY = *(const int4*)(ap + (SIG) * 64 + 4);                     \
  }

#define LOAD_B4(B0_, B1_, B2_, B3_, SIG)                          \
  B0_ = *(const short8*)(bp + (size_t)(SIG) * 8192);              \
  B1_ = *(const short8*)(bp + (size_t)(SIG) * 8192 + 512);        \
  B2_ = *(const short8*)(bp + (size_t)(SIG) * 8192 + 1024);       \
  B3_ = *(const short8*)(bp + (size_t)(SIG) * 8192 + 1536);

#define CW(AX, AY, BUF)                                           \
  {                                                               \
    const uint32_t w01 = (uint32_t)AX.x | ((uint32_t)AX.y << 16); \
    const uint32_t w23 = (uint32_t)AX.z | ((uint32_t)AX.w << 16); \
    const uint32_t w45 = (uint32_t)AY.x | ((uint32_t)AY.y << 16); \
    const uint32_t w67 = (uint32_t)AY.z | ((uint32_t)AY.w << 16); \
    cnt += w01 + w23 + w45 + w67;                                 \
    uint4 d = { w01 * 0x3F80u, w23 * 0x3F80u, w45 * 0x3F80u, w67 * 0x3F80u }; \
    *(uint4*)((char*)ldsA[BUF] + aw) = d;                         \
  }

#define BAR()                                                     \
  asm volatile("s_waitcnt lgkmcnt(0)" ::: "memory");              \
  __builtin_amdgcn_s_barrier();                                   \
  __builtin_amdgcn_sched_barrier(0);

#define MFMA4(BUF, B0_, B1_, B2_, B3_)                            \
  {                                                               \
    const char* Ab = (const char*)ldsA[BUF];                      \
    const short8 af0 = *(const short8*)(Ab + o00);                \
    const short8 af1 = *(const short8*)(Ab + o01);                \
    const short8 ag0 = *(const short8*)(Ab + o10);                \
    const short8 ag1 = *(const short8*)(Ab + o11);                \
    __builtin_amdgcn_s_setprio(1);                                \
    acc00 = __builtin_amdgcn_mfma_f32_16x16x32_bf16(af0, B0_, acc00, 0, 0, 0); \
    acc01 = __builtin_amdgcn_mfma_f32_16x16x32_bf16(af0, B1_, acc01, 0, 0, 0); \
    acc10 = __builtin_amdgcn_mfma_f32_16x16x32_bf16(af1, B0_, acc10, 0, 0, 0); \
    acc11 = __builtin_amdgcn_mfma_f32_16x16x32_bf16(af1, B1_, acc11, 0, 0, 0); \
    acc00 = __builtin_amdgcn_mfma_f32_16x16x32_bf16(ag0, B2_, acc00, 0, 0, 0); \
    acc01 = __builtin_amdgcn_mfma_f32_16x16x32_bf16(ag0, B3_, acc01, 0, 0, 0); \
    acc10 = __builtin_amdgcn_mfma_f32_16x16x32_bf16(ag1, B2_, acc10, 0, 0, 0); \
    acc11 = __builtin_amdgcn_mfma_f32_16x16x32_bf16(ag1, B3_, acc11, 0, 0, 0); \
    __builtin_amdgcn_s_setprio(0);                                \
  }

  // ---- prologue: A stages 0-3 in flight, B stages 0-1, stage 0 into LDS ----
  LOAD_A(a0x, a0y, 0) LOAD_A(a1x, a1y, 1) LOAD_A(a2x, a2y, 2) LOAD_A(a3x, a3y, 3)
  LOAD_B4(t00, t01, t02, t03, 0) LOAD_B4(t10, t11, t12, t13, 1)
  CW(a0x, a0y, 0)
  BAR()

  // ---- 17 static phases ----
  // phase q: LOAD_A(S[q&3], q+4) | LOAD_B(T[(q+2)%3], q+2) | MFMA(buf[q&1], T[q%3])
  //          | CW(S[(q+1)&3] -> buf[(q+1)&1]) | BAR
  /* q0  */ LOAD_A(a0x,a0y,4)  LOAD_B4(t20,t21,t22,t23,2)  MFMA4(0, t00,t01,t02,t03) CW(a1x,a1y,1) BAR()
  /* q1  */ LOAD_A(a1x,a1y,5)  LOAD_B4(t00,t01,t02,t03,3)  MFMA4(1, t10,t11,t12,t13) CW(a2x,a2y,0) BAR()
  /* q2  */ LOAD_A(a2x,a2y,6)  LOAD_B4(t10,t11,t12,t13,4)  MFMA4(0, t20,t21,t22,t23) CW(a3x,a3y,1) BAR()
  /* q3  */ LOAD_A(a3x,a3y,7)  LOAD_B4(t20,t21,t22,t23,5)  MFMA4(1, t00,t01,t02,t03) CW(a0x,a0y,0) BAR()
  /* q4  */ LOAD_A(a0x,a0y,8)  LOAD_B4(t00,t01,t02,t03,6)  MFMA4(0, t10,t11,t12,t13) CW(a1x,a1y,1) BAR()
  /* q5  */ LOAD_A(a1x,a1y,9)  LOAD_B4(t10,t11,t12,t13,7)  MFMA4(1, t20,t21,t22,t23) CW(a2x,a2y,0) BAR()
  /* q6  */ LOAD_A(a2x,a2y,10) LOAD_B4(t20,t21,t22,t23,8)  MFMA4(0, t00,t01,t02,t03) CW(a3x,a3y,1) BAR()
  /* q7  */ LOAD_A(a3x,a3y,11) LOAD_B4(t00,t01,t02,t03,9)  MFMA4(1, t10,t11,t12,t13) CW(a0x,a0y,0) BAR()
  /* q8  */ LOAD_A(a0x,a0y,12) LOAD_B4(t10,t11,t12,t13,10) MFMA4(0, t20,t21,t22,t23) CW(a1x,a1y,1) BAR()
  /* q9  */ LOAD_A(a1x,a1y,13) LOAD_B4(t20,t21,t22,t23,11) MFMA4(1, t00,t01,t02,t03) CW(a2x,a2y,0) BAR()
  /* q10 */ LOAD_A(a2x,a2y,14) LOAD_B4(t00,t01,t02,t03,12) MFMA4(0, t10,t11,t12,t13) CW(a3x,a3y,1) BAR()
  /* q11 */ LOAD_A(a3x,a3y,15) LOAD_B4(t10,t11,t12,t13,13) MFMA4(1, t20,t21,t22,t23) CW(a0x,a0y,0) BAR()
  /* q12 */ LOAD_A(a0x,a0y,16) LOAD_B4(t20,t21,t22,t23,14) MFMA4(0, t00,t01,t02,t03) CW(a1x,a1y,1) BAR()
  /* q13 */                    LOAD_B4(t00,t01,t02,t03,15) MFMA4(1, t10,t11,t12,t13) CW(a2x,a2y,0) BAR()
  /* q14 */                    LOAD_B4(t10,t11,t12,t13,16) MFMA4(0, t20,t21,t22,t23) CW(a3x,a3y,1) BAR()
  /* q15 */                                                MFMA4(1, t00,t01,t02,t03) CW(a0x,a0y,0) BAR()
  /* q16 */                                                MFMA4(0, t10,t11,t12,t13)

#undef LOAD_A
#undef LOAD_B4
#undef CW
#undef BAR
#undef MFMA4

  // ---- epilogue: partial tile [kc][row][col] fp32 ----
  {
    const int jr = (lane >> 4) << 2;                       // C/D row group
    float* pt0 = part + (size_t)kc * (MD * HD)
               + (size_t)(mb * BM + jr) * HD + w * 32 + r16;
#pragma unroll
    for (int j = 0; j < 4; ++j) {
      pt0[j * HD]             = acc00[j];
      pt0[j * HD + 16]        = acc01[j];
      pt0[(16 + j) * HD]      = acc10[j];
      pt0[(16 + j) * HD + 16] = acc11[j];
    }
  }

  // ---- per-row mask counts: 8 consecutive lanes share a row ----
  {
    int c = (int)((cnt & 0xFFFFu) + (cnt >> 16));
    c += __shfl_xor(c, 1);
    c += __shfl_xor(c, 2);
    c += __shfl_xor(c, 4);
    if ((lane & 7) == 0)
      cntp[kc * MD + mb * BM + w * 8 + (lane >> 3)] = (float)c;
  }
}

// ---------------------------------------------------------------------------
// Kernel 3: reduce partials over kc -> path_emb [512][128]
// 512 threads: 4-way kc split (12+12+11+11) + LDS combine.
// ---------------------------------------------------------------------------
__global__ __launch_bounds__(512) void k_reduce(const float* __restrict__ part,
                                                const float* __restrict__ cntp,
                                                float* __restrict__ pe) {
  __shared__ float red[512];
  __shared__ float cred[4];
  const int r   = blockIdx.x;
  const int t   = threadIdx.x;
  const int col = t & 127;
  const int sub = t >> 7;
  const int k0  = (sub < 2) ? sub * 12 : 24 + (sub - 2) * 11;
  const int kn  = (sub < 2) ? 12 : 11;
  const float* pp = part + (size_t)(k0) * (MD * HD) + (size_t)r * HD + col;
  float s = 0.f;
#pragma unroll 4
  for (int i = 0; i < kn; ++i) s += pp[(size_t)i * (MD * HD)];
  red[t] = s;
  if (col == 0) {
    float c = 0.f;
    for (int i = 0; i < kn; ++i) c += cntp[(k0 + i) * MD + r];
    cred[sub] = c;
  }
  __syncthreads();
  if (t < 128) {
    const float tot = red[t] + red[t + 128] + red[t + 256] + red[t + 384];
    const float c   = cred[0] + cred[1] + cred[2] + cred[3];
    pe[r * HD + t] = (c > 0.f) ? (tot / c) : 0.f;
  }
}

// ---------------------------------------------------------------------------
// Kernel 4: mean over P, then LN -> FC1 -> ReLU -> BN -> LN -> FC2 -> ReLU -> BN
// ---------------------------------------------------------------------------
__global__ __launch_bounds__(128) void k_tail(
    const float* __restrict__ pe,
    const float* __restrict__ w1, const float* __restrict__ b1,
    const float* __restrict__ w2, const float* __restrict__ b2,
    const float* __restrict__ ln1g, const float* __restrict__ ln1b,
    const float* __restrict__ ln2g, const float* __restrict__ ln2b,
    const float* __restrict__ bn1g, const float* __restrict__ bn1b,
    const float* __restrict__ bn2g, const float* __restrict__ bn2b,
    float* __restrict__ out) {
  const int b = blockIdx.x, t = threadIdx.x;
  __shared__ float sh[HD];
  __shared__ float red[HD];

  float x = 0.f;
#pragma unroll
  for (int p = 0; p < PD; ++p) x += pe[(b * PD + p) * HD + t];
  x *= (1.f / PD);

  const float bninv = rsqrtf(1.f + EPSF);

  // ---- LN1 ----
  red[t] = x; __syncthreads();
  for (int o = 64; o > 0; o >>= 1) { if (t < o) red[t] += red[t + o]; __syncthreads(); }
  const float mu1 = red[0] * (1.f / HD); __syncthreads();
  const float d1 = x - mu1;
  red[t] = d1 * d1; __syncthreads();
  for (int o = 64; o > 0; o >>= 1) { if (t < o) red[t] += red[t + o]; __syncthreads(); }
  const float v1 = red[0] * (1.f / HD); __syncthreads();
  const float y1 = ln1g[t] * d1 * rsqrtf(v1 + EPSF) + ln1b[t];

  // ---- FC1 + ReLU + BN1 ----
  sh[t] = y1; __syncthreads();
  float a = b1[t];
  const float4* wrow1 = (const float4*)(w1 + (size_t)t * HD);
#pragma unroll 8
  for (int k = 0; k < 32; ++k) {
    const float4 w = wrow1[k];
    a += w.x * sh[k * 4] + w.y * sh[k * 4 + 1] + w.z * sh[k * 4 + 2] + w.w * sh[k * 4 + 3];
  }
  a = fmaxf(a, 0.f);
  a = bn1g[t] * a * bninv + bn1b[t];
  __syncthreads();   // done with sh

  // ---- LN2 ----
  red[t] = a; __syncthreads();
  for (int o = 64; o > 0; o >>= 1) { if (t < o) red[t] += red[t + o]; __syncthreads(); }
  const float mu2 = red[0] * (1.f / HD); __syncthreads();
  const float d2 = a - mu2;
  red[t] = d2 * d2; __syncthreads();
  for (int o = 64; o > 0; o >>= 1) { if (t < o) red[t] += red[t + o]; __syncthreads(); }
  const float v2 = red[0] * (1.f / HD); __syncthreads();
  const float y2 = ln2g[t] * d2 * rsqrtf(v2 + EPSF) + ln2b[t];

  // ---- FC2 + ReLU + BN2 ----
  sh[t] = y2; __syncthreads();
  float a2 = b2[t];
  const float4* wrow2 = (const float4*)(w2 + (size_t)t * HD);
#pragma unroll 8
  for (int k = 0; k < 32; ++k) {
    const float4 w = wrow2[k];
    a2 += w.x * sh[k * 4] + w.y * sh[k * 4 + 1] + w.z * sh[k * 4 + 2] + w.w * sh[k * 4 + 3];
  }
  a2 = fmaxf(a2, 0.f);
  a2 = bn2g[t] * a2 * bninv + bn2b[t];
  out[b * HD + t] = a2;
}

// ---------------------------------------------------------------------------
extern "C" void kernel_launch(void* const* d_in, const int* in_sizes, int n_in,
                              void* d_out, int out_size, void* d_ws, size_t ws_size,
                              hipStream_t stream) {
  const int*   inp  = (const int*)d_in[0];
  const float* emb  = (const float*)d_in[1];
  const float* w1   = (const float*)d_in[2];
  const float* b1   = (const float*)d_in[3];
  const float* w2   = (const float*)d_in[4];
  const float* b2   = (const float*)d_in[5];
  const float* ln1g = (const float*)d_in[6];
  const float* ln1b = (const float*)d_in[7];
  const float* ln2g = (const float*)d_in[8];
  const float* ln2b = (const float*)d_in[9];
  const float* bn1g = (const float*)d_in[10];
  const float* bn1b = (const float*)d_in[11];
  const float* bn2g = (const float*)d_in[12];
  const float* bn2b = (const float*)d_in[13];
  float* out = (float*)d_out;

  // workspace layout (~25.2 MB total)
  char* ws = (char*)d_ws;
  uint16_t* embF = (uint16_t*)ws;                        // 782*16384 = 12,812,288 B
  float* part = (float*)(ws + 12812288);                 // 46*512*128*4 = 12,058,624 B
  float* cntp = (float*)(ws + 12812288 + 12058624);      // 46*512*4 = 94,208 B
  float* pe   = (float*)(ws + 12812288 + 12058624 + 94208); // 512*128*4 = 262,144 B

  k_embF<<<NKC * NST, 256, 0, stream>>>(emb, embF);
  k_gemm<<<NKC * 16, 256, 0, stream>>>(inp, embF, part, cntp);
  k_reduce<<<MD, 512, 0, stream>>>(part, cntp, pe);
  k_tail<<<BD, 128, 0, stream>>>(pe, w1, b1, w2, b2, ln1g, ln1b, ln2g, ln2b,
                                 bn1g, bn1b, bn2g, bn2b, out);
}